// Round 8
// baseline (1088.816 us; speedup 1.0000x reference)
//
#include <hip/hip_runtime.h>
#include <hip/hip_bf16.h>

// ShiftWindowMSA fused pipeline for MI355X (gfx950).
// R8: barrier-free GEMM K-loops. A-slice (one window, 64x384 bf16) resident in
// LDS (48 KB -> 3 blocks/CU); B fragments loaded straight from L2 into
// registers with 3-deep prefetch (no glds, no B-LDS, no in-loop barriers).
// Wave tile 64x32. gemm_qkv grid (nwin,2): var0 -> k,v panels; var1 -> q.
// gemm_proj same structure. attn unchanged.

typedef __attribute__((ext_vector_type(8))) short short8;
typedef __attribute__((ext_vector_type(4))) float floatx4;

#define MFMA16(a, b, c) __builtin_amdgcn_mfma_f32_16x16x32_bf16(a, b, c, 0, 0, 0)

__device__ __forceinline__ short f2bf(float f) {
    __hip_bfloat16 h = __float2bfloat16(f);
    return *reinterpret_cast<short*>(&h);
}

// packed fp32->bf16 RNE
__device__ __forceinline__ unsigned cvt2bf(float lo, float hi) {
    unsigned r;
    asm("v_cvt_pk_bf16_f32 %0, %1, %2" : "=v"(r) : "v"(lo), "v"(hi));
    return r;
}

__device__ __forceinline__ void glds16(const void* g, void* l) {
    __builtin_amdgcn_global_load_lds(
        (const __attribute__((address_space(1))) void*)g,
        (__attribute__((address_space(3))) void*)l, 16, 0, 0);
}

// ---------------- prep kernels ----------------

// Wt[1152][384] bf16: rows 0..767 = cols of W_qkv; 768.. = cols of W_skip * SCALE
__global__ __launch_bounds__(256) void prep_wt(const float* __restrict__ Wqkv,
                                               const float* __restrict__ Wskip,
                                               short* __restrict__ Wt) {
    int tid = blockIdx.x * 256 + threadIdx.x;  // 384*144 = 55296
    if (tid >= 384 * 144) return;
    int k = tid / 144;
    int n8 = (tid % 144) * 8;
#pragma unroll
    for (int e = 0; e < 8; e++) {
        int n = n8 + e;
        float v = (n < 768) ? Wqkv[k * 768 + n]
                            : Wskip[k * 384 + (n - 768)] * 0.17677669529663687f;
        Wt[(size_t)n * 384 + k] = f2bf(v);
    }
}

__global__ __launch_bounds__(256) void prep_wtp(const float* __restrict__ Wproj,
                                                short* __restrict__ WtP) {
    int tid = blockIdx.x * 256 + threadIdx.x;  // 384*48 = 18432
    if (tid >= 384 * 48) return;
    int k = tid / 48;
    int n8 = (tid % 48) * 8;
#pragma unroll
    for (int e = 0; e < 8; e++) {
        int n = n8 + e;
        WtP[(size_t)n * 384 + k] = f2bf(Wproj[k * 384 + n]);
    }
}

// bias64[h][i][kk] = rpb_table[r(i) + r(63-kk)][h],  r(t) = 15*(t>>3) + (t&7)
__global__ __launch_bounds__(256) void prep_bias(const float* __restrict__ rpb,
                                                 float* __restrict__ bias64) {
    int tid = blockIdx.x * 256 + threadIdx.x;  // 12*64*64 = 49152
    if (tid >= 49152) return;
    int h = tid >> 12;
    int rem = tid & 4095;
    int i = rem >> 6, kk = rem & 63;
    int j = 63 - kk;
    int ridx = 15 * (i >> 3) + (i & 7) + 15 * (j >> 3) + (j & 7);
    bias64[tid] = rpb[ridx * 12 + h];
}

// ---------------- shared GEMM panel core ----------------
// A[64][384] bf16 in LDS (chunk-swizzled: chunk c of row r at (c ^ (r&7))).
// B: 2 column-frags per wave, direct global loads, 3-deep prefetch.
// SW=true: acc[a][b] with C-row = B-col (a*16+g4*4+r), C-col = token (b*16+l15)
// SW=false: acc[a][b] with C-row = token (b*16+g4*4+r... see epilogues.
template <bool SW>
__device__ __forceinline__ void gemm_panel(
    const short* __restrict__ sA, const short* __restrict__ Blane0,
    const short* __restrict__ Blane1, int l15, int g4, int al7,
    floatx4 (&acc)[2][4]) {
#pragma unroll
    for (int a = 0; a < 2; a++)
#pragma unroll
        for (int b = 0; b < 4; b++)
#pragma unroll
            for (int r = 0; r < 4; r++) acc[a][b][r] = 0.f;

    short8 bfr[3][2];
#pragma unroll
    for (int s = 0; s < 3; s++) {
        bfr[s][0] = *(const short8*)(Blane0 + s * 32);
        bfr[s][1] = *(const short8*)(Blane1 + s * 32);
    }
#pragma unroll
    for (int kt = 0; kt < 12; ++kt) {
        const int choff = ((kt * 4 + g4) ^ al7) * 8;
        short8 af[4];
#pragma unroll
        for (int b = 0; b < 4; b++)
            af[b] = *(const short8*)(sA + (b * 16 + l15) * 384 + choff);
        short8 b0 = bfr[kt % 3][0], b1 = bfr[kt % 3][1];
        if (kt < 9) {
            bfr[kt % 3][0] = *(const short8*)(Blane0 + (kt + 3) * 32);
            bfr[kt % 3][1] = *(const short8*)(Blane1 + (kt + 3) * 32);
        }
        if (SW) {
#pragma unroll
            for (int b = 0; b < 4; b++) {
                acc[0][b] = MFMA16(b0, af[b], acc[0][b]);
                acc[1][b] = MFMA16(b1, af[b], acc[1][b]);
            }
        } else {
#pragma unroll
            for (int b = 0; b < 4; b++) {
                acc[0][b] = MFMA16(af[b], b0, acc[0][b]);
                acc[1][b] = MFMA16(af[b], b1, acc[1][b]);
            }
        }
    }
}

// ---------------- gemm_qkv ----------------
__global__ __launch_bounds__(256, 3) void gemm_qkv(
    const float* __restrict__ xq, const float* __restrict__ xs,
    const short* __restrict__ Wt,
    const float* __restrict__ bqkv, const float* __restrict__ bskip,
    short* __restrict__ kbuf, short* __restrict__ vtbuf, short* __restrict__ qbuf) {
    __shared__ short smem[24576];  // A[64][384] bf16, 48 KB

    const int win = blockIdx.x;          // one window per block
    const int var = blockIdx.y;          // 0: A=query -> k,v; 1: A=skip -> q
    const float* __restrict__ src = var ? xs : xq;

    const int tid = threadIdx.x, lane = tid & 63, wid = tid >> 6;
    const int l15 = lane & 15, g4 = lane >> 4;
    const int al7 = l15 & 7;

    // ---- A gather: 64 rows x 384 fp32 (shift-window permuted) -> bf16 LDS ----
    {
        int r = tid >> 2, q4 = tid & 3;
        int b = win / 144, wr = win % 144;
        int wy = wr / 12, wx = wr % 12;
        int yy = wy * 8 + (r >> 3) + 4; if (yy >= 96) yy -= 96;
        int xx = wx * 8 + (r & 7) + 4;  if (xx >= 96) xx -= 96;
        const float* rbase = src + ((size_t)b * 9216 + yy * 96 + xx) * 384;
        short* lrow = smem + r * 384;
        int r7 = r & 7;
#pragma unroll
        for (int j = 0; j < 12; j++) {
            int c = q4 + j * 4;
            float4 f0 = *(const float4*)(rbase + c * 8);
            float4 f1 = *(const float4*)(rbase + c * 8 + 4);
            uint4 u;
            u.x = cvt2bf(f0.x, f0.y); u.y = cvt2bf(f0.z, f0.w);
            u.z = cvt2bf(f1.x, f1.y); u.w = cvt2bf(f1.z, f1.w);
            *(uint4*)(lrow + ((c ^ r7) * 8)) = u;
        }
    }
    __syncthreads();  // only barrier; A is read-only afterwards

    if (var == 0) {
        // ---- k panels 0..2 (swapped) ----
        for (int nb = 0; nb < 3; ++nb) {
            const short* Bl0 = Wt + (size_t)(nb * 128 + wid * 32 + l15) * 384 + g4 * 8;
            const short* Bl1 = Bl0 + 16 * 384;
            floatx4 acc[2][4];
            gemm_panel<true>(smem, Bl0, Bl1, l15, g4, al7, acc);
            const int ncol0 = nb * 128 + wid * 32;
#pragma unroll
            for (int a = 0; a < 2; a++) {
                int nm = ncol0 + a * 16 + g4 * 4;
                int head = nm >> 5, d0 = nm & 31;
                float4 bv = *(const float4*)(bqkv + nm);
                short* dst = kbuf + (size_t)(win * 12 + head) * 2048 + d0;
#pragma unroll
                for (int b = 0; b < 4; b++) {
                    int t = b * 16 + l15;
                    uint2 pk;
                    pk.x = cvt2bf(acc[a][b][0] + bv.x, acc[a][b][1] + bv.y);
                    pk.y = cvt2bf(acc[a][b][2] + bv.z, acc[a][b][3] + bv.w);
                    *(uint2*)(dst + (size_t)t * 32) = pk;
                }
            }
        }
        // ---- v panels 3..5 (unswapped) ----
        for (int nb = 3; nb < 6; ++nb) {
            const short* Bl0 = Wt + (size_t)(nb * 128 + wid * 32 + l15) * 384 + g4 * 8;
            const short* Bl1 = Bl0 + 16 * 384;
            floatx4 acc[2][4];  // [nj][mi]: t = mi*16+g4*4+r, d-col = nj*16+l15
            gemm_panel<false>(smem, Bl0, Bl1, l15, g4, al7, acc);
            const int ncol0 = nb * 128 + wid * 32;
#pragma unroll
            for (int nj = 0; nj < 2; nj++) {
                int nm = ncol0 + nj * 16 + l15 - 384;
                int head = nm >> 5, d = nm & 31;
                float bvs = bqkv[384 + nm];
                short* dst = vtbuf + ((size_t)(win * 12 + head) * 32 + d) * 64;
#pragma unroll
                for (int mi = 0; mi < 4; mi++) {
                    int t0 = mi * 16 + g4 * 4;
                    uint2 pk;
                    pk.x = cvt2bf(acc[nj][mi][0] + bvs, acc[nj][mi][1] + bvs);
                    pk.y = cvt2bf(acc[nj][mi][2] + bvs, acc[nj][mi][3] + bvs);
                    *(uint2*)(dst + t0) = pk;
                }
            }
        }
    } else {
        // ---- q panels 6..8 (swapped; W pre-scaled, bias scaled here) ----
        for (int nb = 6; nb < 9; ++nb) {
            const short* Bl0 = Wt + (size_t)(nb * 128 + wid * 32 + l15) * 384 + g4 * 8;
            const short* Bl1 = Bl0 + 16 * 384;
            floatx4 acc[2][4];
            gemm_panel<true>(smem, Bl0, Bl1, l15, g4, al7, acc);
            const int ncol0 = nb * 128 + wid * 32;
            const float scl = 0.17677669529663687f;
#pragma unroll
            for (int a = 0; a < 2; a++) {
                int nm = ncol0 + a * 16 + g4 * 4 - 768;
                int head = nm >> 5, d0 = nm & 31;
                float4 bv = *(const float4*)(bskip + nm);
                short* dst = qbuf + (size_t)(win * 12 + head) * 2048 + d0;
#pragma unroll
                for (int b = 0; b < 4; b++) {
                    int t = b * 16 + l15;
                    uint2 pk;
                    pk.x = cvt2bf(acc[a][b][0] + bv.x * scl, acc[a][b][1] + bv.y * scl);
                    pk.y = cvt2bf(acc[a][b][2] + bv.z * scl, acc[a][b][3] + bv.w * scl);
                    *(uint2*)(dst + (size_t)t * 32) = pk;
                }
            }
        }
    }
}

// ---------------- attention ----------------
__global__ __launch_bounds__(256) void attn_kernel(
    const short* __restrict__ kbuf, const short* __restrict__ vtbuf,
    const short* __restrict__ qbuf, const float* __restrict__ bias64,
    short* __restrict__ aout, int ntask) {
    __shared__ short lps[18432];  // 4 waves x 64 x 72
    int lane = threadIdx.x & 63, wid = threadIdx.x >> 6;
    int task = blockIdx.x * 4 + wid;
    if (task >= ntask) return;
    int win = task / 12, head = task % 12;
    int l15 = lane & 15, g4 = lane >> 4;

    const short* kb = kbuf + (size_t)task * 2048;
    const short* qb = qbuf + (size_t)task * 2048;
    const short* vb = vtbuf + (size_t)task * 2048;

    short8 kf[4], qf[4], vf[2][2];
#pragma unroll
    for (int mi = 0; mi < 4; mi++)
        kf[mi] = *(const short8*)(kb + (mi * 16 + l15) * 32 + g4 * 8);
#pragma unroll
    for (int nj = 0; nj < 4; nj++)
        qf[nj] = *(const short8*)(qb + (nj * 16 + l15) * 32 + g4 * 8);
#pragma unroll
    for (int ma = 0; ma < 2; ma++)
#pragma unroll
        for (int ks = 0; ks < 2; ks++)
            vf[ma][ks] = *(const short8*)(vb + (ma * 16 + l15) * 64 + ks * 32 + g4 * 8);

    floatx4 st[4][4];
#pragma unroll
    for (int mi = 0; mi < 4; mi++)
#pragma unroll
        for (int nj = 0; nj < 4; nj++)
#pragma unroll
            for (int r = 0; r < 4; r++) st[mi][nj][r] = 0.f;

#pragma unroll
    for (int mi = 0; mi < 4; mi++)
#pragma unroll
        for (int nj = 0; nj < 4; nj++)
            st[mi][nj] = MFMA16(kf[mi], qf[nj], st[mi][nj]);  // S^T[kk][i]

    const float* bb = bias64 + head * 4096;
#pragma unroll
    for (int nj = 0; nj < 4; nj++) {
        int i = nj * 16 + l15;
#pragma unroll
        for (int mi = 0; mi < 4; mi++) {
            floatx4 b4 = *(const floatx4*)(bb + i * 64 + mi * 16 + g4 * 4);
            st[mi][nj] += b4;
        }
    }

    int wr = win % 144;
    int wy = wr / 12, wx = wr % 12;
    if (wy == 11 || wx == 11) {
        int wy11 = (wy == 11), wx11 = (wx == 11);
        int ri[4];
#pragma unroll
        for (int nj = 0; nj < 4; nj++) {
            int t = nj * 16 + l15;
            int hh = wy11 ? (((t >> 3) >= 4) ? 2 : 1) : 0;
            int ww = wx11 ? (((t & 7) >= 4) ? 2 : 1) : 0;
            ri[nj] = hh * 3 + ww;
        }
#pragma unroll
        for (int mi = 0; mi < 4; mi++)
#pragma unroll
            for (int r = 0; r < 4; r++) {
                int t = mi * 16 + g4 * 4 + r;
                int hh = wy11 ? (((t >> 3) >= 4) ? 2 : 1) : 0;
                int ww = wx11 ? (((t & 7) >= 4) ? 2 : 1) : 0;
                int rk = hh * 3 + ww;
#pragma unroll
                for (int nj = 0; nj < 4; nj++)
                    if (rk != ri[nj]) st[mi][nj][r] -= 100.0f;
            }
    }

    float rden[4];
#pragma unroll
    for (int nj = 0; nj < 4; nj++) {
        float m = -1e30f;
#pragma unroll
        for (int mi = 0; mi < 4; mi++)
#pragma unroll
            for (int r = 0; r < 4; r++) m = fmaxf(m, st[mi][nj][r]);
        m = fmaxf(m, __shfl_xor(m, 16));
        m = fmaxf(m, __shfl_xor(m, 32));
        float s = 0.f;
#pragma unroll
        for (int mi = 0; mi < 4; mi++)
#pragma unroll
            for (int r = 0; r < 4; r++) {
                float p = __expf(st[mi][nj][r] - m);
                st[mi][nj][r] = p;
                s += p;
            }
        s += __shfl_xor(s, 16);
        s += __shfl_xor(s, 32);
        rden[nj] = 1.0f / s;
    }

    short* Lp = lps + wid * 4608;  // [64][72]
#pragma unroll
    for (int mi = 0; mi < 4; mi++)
#pragma unroll
        for (int nj = 0; nj < 4; nj++) {
            uint2 pk;
            pk.x = cvt2bf(st[mi][nj][0], st[mi][nj][1]);
            pk.y = cvt2bf(st[mi][nj][2], st[mi][nj][3]);
            *(uint2*)(Lp + (nj * 16 + l15) * 72 + mi * 16 + g4 * 4) = pk;
        }

    floatx4 o[2][4];
#pragma unroll
    for (int ma = 0; ma < 2; ma++)
#pragma unroll
        for (int nj = 0; nj < 4; nj++)
#pragma unroll
            for (int r = 0; r < 4; r++) o[ma][nj][r] = 0.f;
#pragma unroll
    for (int ks = 0; ks < 2; ks++) {
        short8 pb[4];
#pragma unroll
        for (int nj = 0; nj < 4; nj++)
            pb[nj] = *(const short8*)(Lp + (nj * 16 + l15) * 72 + ks * 32 + g4 * 8);
#pragma unroll
        for (int ma = 0; ma < 2; ma++)
#pragma unroll
            for (int nj = 0; nj < 4; nj++)
                o[ma][nj] = MFMA16(vf[ma][ks], pb[nj], o[ma][nj]);
    }

    short* ob = aout + (size_t)win * 64 * 384 + head * 32;
#pragma unroll
    for (int ma = 0; ma < 2; ma++)
#pragma unroll
        for (int nj = 0; nj < 4; nj++) {
            int i = nj * 16 + l15;
            uint2 pk;
            pk.x = cvt2bf(o[ma][nj][0] * rden[nj], o[ma][nj][1] * rden[nj]);
            pk.y = cvt2bf(o[ma][nj][2] * rden[nj], o[ma][nj][3] * rden[nj]);
            *(uint2*)(ob + (size_t)i * 384 + ma * 16 + g4 * 4) = pk;
        }
}

// ---------------- gemm_proj ----------------
__global__ __launch_bounds__(256, 3) void gemm_proj(
    const short* __restrict__ aout, const short* __restrict__ WtP,
    const float* __restrict__ bproj, float* __restrict__ out) {
    __shared__ short smem[24576];  // A[64][384] bf16

    const int win = blockIdx.x;
    const int m0 = win * 64;
    const int tid = threadIdx.x, lane = tid & 63, wid = tid >> 6;
    const int l15 = lane & 15, g4 = lane >> 4;
    const int al7 = l15 & 7;

    // ---- A via glds: 48 issues of 1KB (12 per wave), pre-swizzled source ----
#pragma unroll
    for (int j = 0; j < 12; j++) {
        int i = wid * 12 + j;
        int c = i * 64 + lane;
        int row = c / 48, ch = c - row * 48;
        const short* s = aout + (size_t)(m0 + row) * 384 + ((ch ^ (row & 7)) * 8);
        glds16(s, smem + i * 512);
    }
    asm volatile("s_waitcnt vmcnt(0)" ::: "memory");
    __syncthreads();

    const int b_img = win / 144, wrw = win % 144;
    const int wy = wrw / 12, wx = wrw % 12;

    for (int pb = 0; pb < 3; ++pb) {
        const short* Bl0 = WtP + (size_t)(pb * 128 + wid * 32 + l15) * 384 + g4 * 8;
        const short* Bl1 = Bl0 + 16 * 384;
        floatx4 acc[2][4];
        gemm_panel<true>(smem, Bl0, Bl1, l15, g4, al7, acc);
#pragma unroll
        for (int a = 0; a < 2; a++) {
            int n = pb * 128 + wid * 32 + a * 16 + g4 * 4;
            float4 bv = *(const float4*)(bproj + n);
#pragma unroll
            for (int b = 0; b < 4; b++) {
                int t = b * 16 + l15;
                int yy = wy * 8 + (t >> 3) + 4; if (yy >= 96) yy -= 96;
                int xx = wx * 8 + (t & 7) + 4;  if (xx >= 96) xx -= 96;
                floatx4 o = acc[a][b];
                o[0] += bv.x; o[1] += bv.y; o[2] += bv.z; o[3] += bv.w;
                *(floatx4*)(&out[((size_t)b_img * 9216 + yy * 96 + xx) * 384 + n]) = o;
            }
        }
    }
}

// ---------------- launcher ----------------
extern "C" void kernel_launch(void* const* d_in, const int* in_sizes, int n_in,
                              void* d_out, int out_size, void* d_ws, size_t ws_size,
                              hipStream_t stream) {
    const float* query = (const float*)d_in[0];
    const float* skipq = (const float*)d_in[1];
    const float* Wqkv  = (const float*)d_in[2];
    const float* bqkv  = (const float*)d_in[3];
    const float* Wskip = (const float*)d_in[4];
    const float* bskip = (const float*)d_in[5];
    const float* rpb   = (const float*)d_in[6];
    const float* Wproj = (const float*)d_in[7];
    const float* bproj = (const float*)d_in[8];
    float* out = (float*)d_out;

    int M = in_sizes[0] / 384;   // total tokens = 147456 for B=16
    int nwin = M / 64;           // 2304

    char* ws = (char*)d_ws;
    size_t off = 0;
    auto alloc = [&](size_t bytes) -> void* {
        void* p = ws + off;
        off = (off + bytes + 255) & ~(size_t)255;
        return p;
    };
    short* Wt     = (short*)alloc((size_t)1152 * 384 * 2);
    short* WtP    = (short*)alloc((size_t)384 * 384 * 2);
    float* bias64 = (float*)alloc((size_t)12 * 64 * 64 * 4);
    short* kbuf   = (short*)alloc((size_t)M * 384 * 2);
    short* vtbuf  = (short*)alloc((size_t)M * 384 * 2);
    short* qbuf   = (short*)alloc((size_t)M * 384 * 2);
    short* aout   = (short*)alloc((size_t)M * 384 * 2);
    (void)ws_size;

    hipLaunchKernelGGL(prep_wt, dim3(216), dim3(256), 0, stream, Wqkv, Wskip, Wt);
    hipLaunchKernelGGL(prep_wtp, dim3(72), dim3(256), 0, stream, Wproj, WtP);
    hipLaunchKernelGGL(prep_bias, dim3(192), dim3(256), 0, stream, rpb, bias64);
    hipLaunchKernelGGL(gemm_qkv, dim3(nwin, 2), dim3(256), 0, stream,
                       query, skipq, Wt, bqkv, bskip, kbuf, vtbuf, qbuf);
    hipLaunchKernelGGL(attn_kernel, dim3(nwin * 12 / 4), dim3(256), 0, stream,
                       kbuf, vtbuf, qbuf, bias64, aout, nwin * 12);
    hipLaunchKernelGGL(gemm_proj, dim3(nwin), dim3(256), 0, stream,
                       aout, WtP, bproj, out);
}

// Round 9
// 709.420 us; speedup vs baseline: 1.5348x; 1.5348x over previous
//
#include <hip/hip_runtime.h>
#include <hip/hip_bf16.h>

// ShiftWindowMSA fused pipeline for MI355X (gfx950).
// R9: R7 skeleton (A window-slice resident in LDS, B staged via glds, counted
// waits) with 256-col panels / 64x64 wave tiles (half the LDS traffic per MFMA,
// half the barrier events) and the T3 2-phase schedule. B back through LDS
// (R8's reg-B re-fetched from HBM). 80 KB LDS -> 2 blocks/CU.

typedef __attribute__((ext_vector_type(8))) short short8;
typedef __attribute__((ext_vector_type(4))) float floatx4;

#define MFMA16(a, b, c) __builtin_amdgcn_mfma_f32_16x16x32_bf16(a, b, c, 0, 0, 0)

__device__ __forceinline__ short f2bf(float f) {
    __hip_bfloat16 h = __float2bfloat16(f);
    return *reinterpret_cast<short*>(&h);
}

// packed fp32->bf16 RNE
__device__ __forceinline__ unsigned cvt2bf(float lo, float hi) {
    unsigned r;
    asm("v_cvt_pk_bf16_f32 %0, %1, %2" : "=v"(r) : "v"(lo), "v"(hi));
    return r;
}

__device__ __forceinline__ void glds16(const void* g, void* l) {
    __builtin_amdgcn_global_load_lds(
        (const __attribute__((address_space(1))) void*)g,
        (__attribute__((address_space(3))) void*)l, 16, 0, 0);
}

// ---------------- prep kernels ----------------

__global__ __launch_bounds__(256) void prep_wt(const float* __restrict__ Wqkv,
                                               const float* __restrict__ Wskip,
                                               short* __restrict__ Wt) {
    int tid = blockIdx.x * 256 + threadIdx.x;  // 384*144 = 55296
    if (tid >= 384 * 144) return;
    int k = tid / 144;
    int n8 = (tid % 144) * 8;
#pragma unroll
    for (int e = 0; e < 8; e++) {
        int n = n8 + e;
        float v = (n < 768) ? Wqkv[k * 768 + n]
                            : Wskip[k * 384 + (n - 768)] * 0.17677669529663687f;
        Wt[(size_t)n * 384 + k] = f2bf(v);
    }
}

__global__ __launch_bounds__(256) void prep_wtp(const float* __restrict__ Wproj,
                                                short* __restrict__ WtP) {
    int tid = blockIdx.x * 256 + threadIdx.x;  // 384*48 = 18432
    if (tid >= 384 * 48) return;
    int k = tid / 48;
    int n8 = (tid % 48) * 8;
#pragma unroll
    for (int e = 0; e < 8; e++) {
        int n = n8 + e;
        WtP[(size_t)n * 384 + k] = f2bf(Wproj[k * 384 + n]);
    }
}

__global__ __launch_bounds__(256) void prep_bias(const float* __restrict__ rpb,
                                                 float* __restrict__ bias64) {
    int tid = blockIdx.x * 256 + threadIdx.x;  // 12*64*64 = 49152
    if (tid >= 49152) return;
    int h = tid >> 12;
    int rem = tid & 4095;
    int i = rem >> 6, kk = rem & 63;
    int j = 63 - kk;
    int ridx = 15 * (i >> 3) + (i & 7) + 15 * (j >> 3) + (j & 7);
    bias64[tid] = rpb[ridx * 12 + h];
}

// ---------------- panel K-loop (shared by qkv / proj) ----------------
// A[64][384] bf16 in smem[0..24576), chunk-swizzled (c ^ (r&7)).
// B tile staged double-buffered at smem[24576 + half*8192], rows chunk-swizzled
// (2-bit: bs ^ ((brow^(brow>>2))&3)). T3 2-phase: stage(kt+1) -> compute(kt)
// -> sched_barrier + vmcnt(0) + s_barrier. Panel entry requires (kt=0, half0)
// already staged and barriered.
template <int NF>
__device__ __forceinline__ void panel_k(
    short* smem, const short* __restrict__ bcur, const short* __restrict__ bnext,
    const int* broC, const int* bdsC, int niC,
    const int* broN, const int* bdsN, int niN,
    int fragbase, int l15, int g4, int al7, int xsw, bool swapped,
    floatx4 (&acc)[NF][4]) {
#pragma unroll
    for (int a = 0; a < NF; a++)
#pragma unroll
        for (int b = 0; b < 4; b++)
#pragma unroll
            for (int r = 0; r < 4; r++) acc[a][b][r] = 0.f;

    int brof[NF];
#pragma unroll
    for (int nj = 0; nj < NF; nj++)
        brof[nj] = 24576 + (fragbase + nj * 16 + l15) * 32 + xsw;

#pragma unroll
    for (int kt = 0; kt < 12; ++kt) {
        if (kt < 11) {
            int k0 = (kt + 1) * 32;
            int hb = ((kt + 1) & 1) * 8192;
            for (int j = 0; j < niC; j++)
                glds16(bcur + broC[j] + k0, smem + 24576 + hb + bdsC[j]);
        } else if (bnext) {
            for (int j = 0; j < niN; j++)
                glds16(bnext + broN[j], smem + 24576 + bdsN[j]);  // half 0
        }
        int hb = (kt & 1) * 8192;
        const int choff = ((kt * 4 + g4) ^ al7) * 8;
        short8 af[4], bfr[NF];
#pragma unroll
        for (int b = 0; b < 4; b++)
            af[b] = *(const short8*)(smem + (b * 16 + l15) * 384 + choff);
#pragma unroll
        for (int nj = 0; nj < NF; nj++)
            bfr[nj] = *(const short8*)(smem + hb + brof[nj]);
        if (swapped) {
#pragma unroll
            for (int a = 0; a < NF; a++)
#pragma unroll
                for (int b = 0; b < 4; b++)
                    acc[a][b] = MFMA16(bfr[a], af[b], acc[a][b]);
        } else {
#pragma unroll
            for (int a = 0; a < NF; a++)
#pragma unroll
                for (int b = 0; b < 4; b++)
                    acc[a][b] = MFMA16(af[b], bfr[a], acc[a][b]);
        }
        __builtin_amdgcn_sched_barrier(0);
        asm volatile("s_waitcnt vmcnt(0)" ::: "memory");
        __builtin_amdgcn_s_barrier();
    }
}

// ---------------- gemm_qkv ----------------
// LDS: A[64][384] 48 KB + B dbuf 2x16 KB = 80 KB -> 2 blocks/CU.
// var0 (A=query): p0 [0,256) k; p1 [256,512) waves0-1 k / waves2-3 v; p2 [512,768) v.
// var1 (A=skip):  p0 [768,1024) q (NF4); p1 [1024,1152) q (NF2).
__global__ __launch_bounds__(256, 2) void gemm_qkv(
    const float* __restrict__ xq, const float* __restrict__ xs,
    const short* __restrict__ Wt,
    const float* __restrict__ bqkv, const float* __restrict__ bskip,
    short* __restrict__ kbuf, short* __restrict__ vtbuf, short* __restrict__ qbuf) {
    __shared__ short smem[40960];

    const int win = blockIdx.x;
    const int var = blockIdx.y;
    const float* __restrict__ src = var ? xs : xq;

    const int tid = threadIdx.x, lane = tid & 63, wid = tid >> 6;
    const int l15 = lane & 15, g4 = lane >> 4;
    const int al7 = l15 & 7;
    const int xsw = (g4 ^ ((l15 ^ (l15 >> 2)) & 3)) * 8;

    // ---- A gather: 64 rows x 384 fp32 (shift-window permuted) -> bf16 LDS ----
    {
        int r = tid >> 2, q4 = tid & 3;
        int b = win / 144, wr = win % 144;
        int wy = wr / 12, wx = wr % 12;
        int yy = wy * 8 + (r >> 3) + 4; if (yy >= 96) yy -= 96;
        int xx = wx * 8 + (r & 7) + 4;  if (xx >= 96) xx -= 96;
        const float* rbase = src + ((size_t)b * 9216 + yy * 96 + xx) * 384;
        short* lrow = smem + r * 384;
        int r7 = r & 7;
#pragma unroll
        for (int j = 0; j < 12; j++) {
            int c = q4 + j * 4;
            float4 f0 = *(const float4*)(rbase + c * 8);
            float4 f1 = *(const float4*)(rbase + c * 8 + 4);
            uint4 u;
            u.x = cvt2bf(f0.x, f0.y); u.y = cvt2bf(f0.z, f0.w);
            u.z = cvt2bf(f1.x, f1.y); u.w = cvt2bf(f1.z, f1.w);
            *(uint4*)(lrow + ((c ^ r7) * 8)) = u;
        }
    }

    // ---- B staging roles ----
    int bro4[4], bds4[4], bro2[2], bds2[2];
#pragma unroll
    for (int j = 0; j < 4; j++) {
        int i = wid * 4 + j;
        int c = i * 64 + lane;
        int brow = c >> 2, bs = c & 3;
        int sw = (brow ^ (brow >> 2)) & 3;
        bro4[j] = brow * 384 + (bs ^ sw) * 8;
        bds4[j] = i * 512 + lane * 8;
    }
#pragma unroll
    for (int j = 0; j < 2; j++) {
        int i = wid * 2 + j;
        int c = i * 64 + lane;
        int brow = c >> 2, bs = c & 3;
        int sw = (brow ^ (brow >> 2)) & 3;
        bro2[j] = brow * 384 + (bs ^ sw) * 8;
        bds2[j] = i * 512 + lane * 8;
    }

    const short* b0 = Wt + (size_t)(var ? 768 : 0) * 384;
#pragma unroll
    for (int j = 0; j < 4; j++) glds16(b0 + bro4[j], smem + 24576 + bds4[j]);
    __syncthreads();

    // epilogue helpers (inline lambdas)
    auto epi_kq = [&](floatx4(&acc)[4][4], int n0w, short* buf,
                      const float* bias, float scl, int nsub) {
#pragma unroll
        for (int a = 0; a < 4; a++) {
            int nm = n0w + a * 16 + g4 * 4 - nsub;
            int head = nm >> 5, d0 = nm & 31;
            float4 bv = *(const float4*)(bias + nm);
            short* dst = buf + (size_t)(win * 12 + head) * 2048 + d0;
#pragma unroll
            for (int b = 0; b < 4; b++) {
                int t = b * 16 + l15;
                uint2 pk;
                pk.x = cvt2bf(acc[a][b][0] + bv.x * scl, acc[a][b][1] + bv.y * scl);
                pk.y = cvt2bf(acc[a][b][2] + bv.z * scl, acc[a][b][3] + bv.w * scl);
                *(uint2*)(dst + (size_t)t * 32) = pk;
            }
        }
    };
    auto epi_v = [&](floatx4(&acc)[4][4], int n0w) {
#pragma unroll
        for (int nj = 0; nj < 4; nj++) {
            int nm = n0w + nj * 16 + l15 - 384;
            int head = nm >> 5, d = nm & 31;
            float bvs = bqkv[384 + nm];
            short* dst = vtbuf + ((size_t)(win * 12 + head) * 32 + d) * 64;
#pragma unroll
            for (int mi = 0; mi < 4; mi++) {
                int t0 = mi * 16 + g4 * 4;
                uint2 pk;
                pk.x = cvt2bf(acc[nj][mi][0] + bvs, acc[nj][mi][1] + bvs);
                pk.y = cvt2bf(acc[nj][mi][2] + bvs, acc[nj][mi][3] + bvs);
                *(uint2*)(dst + t0) = pk;
            }
        }
    };

    const float scl = 0.17677669529663687f;
    if (var == 0) {
        floatx4 acc[4][4];
        const short* b1 = Wt + (size_t)256 * 384;
        const short* b2 = Wt + (size_t)512 * 384;
        // p0: k
        panel_k<4>(smem, b0, b1, bro4, bds4, 4, bro4, bds4, 4,
                   wid * 64, l15, g4, al7, xsw, true, acc);
        epi_kq(acc, wid * 64, kbuf, bqkv, 1.0f, 0);
        // p1: mixed k/v
        bool swp = (wid < 2);
        panel_k<4>(smem, b1, b2, bro4, bds4, 4, bro4, bds4, 4,
                   wid * 64, l15, g4, al7, xsw, swp, acc);
        if (swp) epi_kq(acc, 256 + wid * 64, kbuf, bqkv, 1.0f, 0);
        else     epi_v(acc, 256 + wid * 64);
        // p2: v
        panel_k<4>(smem, b2, nullptr, bro4, bds4, 4, bro4, bds4, 4,
                   wid * 64, l15, g4, al7, xsw, false, acc);
        epi_v(acc, 512 + wid * 64);
    } else {
        floatx4 acc[4][4];
        const short* b1 = Wt + (size_t)1024 * 384;
        // p0: q, NF4
        panel_k<4>(smem, b0, b1, bro4, bds4, 4, bro2, bds2, 2,
                   wid * 64, l15, g4, al7, xsw, true, acc);
        epi_kq(acc, 768 + wid * 64, qbuf, bskip, scl, 768);
        // p1: q, NF2
        floatx4 a2[2][4];
        panel_k<2>(smem, b1, nullptr, bro2, bds2, 2, bro2, bds2, 2,
                   wid * 32, l15, g4, al7, xsw, true, a2);
#pragma unroll
        for (int a = 0; a < 2; a++) {
            int nm = 1024 + wid * 32 + a * 16 + g4 * 4 - 768;
            int head = nm >> 5, d0 = nm & 31;
            float4 bv = *(const float4*)(bskip + nm);
            short* dst = qbuf + (size_t)(win * 12 + head) * 2048 + d0;
#pragma unroll
            for (int b = 0; b < 4; b++) {
                int t = b * 16 + l15;
                uint2 pk;
                pk.x = cvt2bf(a2[a][b][0] + bv.x * scl, a2[a][b][1] + bv.y * scl);
                pk.y = cvt2bf(a2[a][b][2] + bv.z * scl, a2[a][b][3] + bv.w * scl);
                *(uint2*)(dst + (size_t)t * 32) = pk;
            }
        }
    }
}

// ---------------- attention ----------------
__global__ __launch_bounds__(256) void attn_kernel(
    const short* __restrict__ kbuf, const short* __restrict__ vtbuf,
    const short* __restrict__ qbuf, const float* __restrict__ bias64,
    short* __restrict__ aout, int ntask) {
    __shared__ short lps[18432];  // 4 waves x 64 x 72
    int lane = threadIdx.x & 63, wid = threadIdx.x >> 6;
    int task = blockIdx.x * 4 + wid;
    if (task >= ntask) return;
    int win = task / 12, head = task % 12;
    int l15 = lane & 15, g4 = lane >> 4;

    const short* kb = kbuf + (size_t)task * 2048;
    const short* qb = qbuf + (size_t)task * 2048;
    const short* vb = vtbuf + (size_t)task * 2048;

    short8 kf[4], qf[4], vf[2][2];
#pragma unroll
    for (int mi = 0; mi < 4; mi++)
        kf[mi] = *(const short8*)(kb + (mi * 16 + l15) * 32 + g4 * 8);
#pragma unroll
    for (int nj = 0; nj < 4; nj++)
        qf[nj] = *(const short8*)(qb + (nj * 16 + l15) * 32 + g4 * 8);
#pragma unroll
    for (int ma = 0; ma < 2; ma++)
#pragma unroll
        for (int ks = 0; ks < 2; ks++)
            vf[ma][ks] = *(const short8*)(vb + (ma * 16 + l15) * 64 + ks * 32 + g4 * 8);

    floatx4 st[4][4];
#pragma unroll
    for (int mi = 0; mi < 4; mi++)
#pragma unroll
        for (int nj = 0; nj < 4; nj++)
#pragma unroll
            for (int r = 0; r < 4; r++) st[mi][nj][r] = 0.f;

#pragma unroll
    for (int mi = 0; mi < 4; mi++)
#pragma unroll
        for (int nj = 0; nj < 4; nj++)
            st[mi][nj] = MFMA16(kf[mi], qf[nj], st[mi][nj]);  // S^T[kk][i]

    const float* bb = bias64 + head * 4096;
#pragma unroll
    for (int nj = 0; nj < 4; nj++) {
        int i = nj * 16 + l15;
#pragma unroll
        for (int mi = 0; mi < 4; mi++) {
            floatx4 b4 = *(const floatx4*)(bb + i * 64 + mi * 16 + g4 * 4);
            st[mi][nj] += b4;
        }
    }

    int wr = win % 144;
    int wy = wr / 12, wx = wr % 12;
    if (wy == 11 || wx == 11) {
        int wy11 = (wy == 11), wx11 = (wx == 11);
        int ri[4];
#pragma unroll
        for (int nj = 0; nj < 4; nj++) {
            int t = nj * 16 + l15;
            int hh = wy11 ? (((t >> 3) >= 4) ? 2 : 1) : 0;
            int ww = wx11 ? (((t & 7) >= 4) ? 2 : 1) : 0;
            ri[nj] = hh * 3 + ww;
        }
#pragma unroll
        for (int mi = 0; mi < 4; mi++)
#pragma unroll
            for (int r = 0; r < 4; r++) {
                int t = mi * 16 + g4 * 4 + r;
                int hh = wy11 ? (((t >> 3) >= 4) ? 2 : 1) : 0;
                int ww = wx11 ? (((t & 7) >= 4) ? 2 : 1) : 0;
                int rk = hh * 3 + ww;
#pragma unroll
                for (int nj = 0; nj < 4; nj++)
                    if (rk != ri[nj]) st[mi][nj][r] -= 100.0f;
            }
    }

    float rden[4];
#pragma unroll
    for (int nj = 0; nj < 4; nj++) {
        float m = -1e30f;
#pragma unroll
        for (int mi = 0; mi < 4; mi++)
#pragma unroll
            for (int r = 0; r < 4; r++) m = fmaxf(m, st[mi][nj][r]);
        m = fmaxf(m, __shfl_xor(m, 16));
        m = fmaxf(m, __shfl_xor(m, 32));
        float s = 0.f;
#pragma unroll
        for (int mi = 0; mi < 4; mi++)
#pragma unroll
            for (int r = 0; r < 4; r++) {
                float p = __expf(st[mi][nj][r] - m);
                st[mi][nj][r] = p;
                s += p;
            }
        s += __shfl_xor(s, 16);
        s += __shfl_xor(s, 32);
        rden[nj] = 1.0f / s;
    }

    short* Lp = lps + wid * 4608;  // [64][72]
#pragma unroll
    for (int mi = 0; mi < 4; mi++)
#pragma unroll
        for (int nj = 0; nj < 4; nj++) {
            uint2 pk;
            pk.x = cvt2bf(st[mi][nj][0], st[mi][nj][1]);
            pk.y = cvt2bf(st[mi][nj][2], st[mi][nj][3]);
            *(uint2*)(Lp + (nj * 16 + l15) * 72 + mi * 16 + g4 * 4) = pk;
        }

    floatx4 o[2][4];
#pragma unroll
    for (int ma = 0; ma < 2; ma++)
#pragma unroll
        for (int nj = 0; nj < 4; nj++)
#pragma unroll
            for (int r = 0; r < 4; r++) o[ma][nj][r] = 0.f;
#pragma unroll
    for (int ks = 0; ks < 2; ks++) {
        short8 pb[4];
#pragma unroll
        for (int nj = 0; nj < 4; nj++)
            pb[nj] = *(const short8*)(Lp + (nj * 16 + l15) * 72 + ks * 32 + g4 * 8);
#pragma unroll
        for (int ma = 0; ma < 2; ma++)
#pragma unroll
            for (int nj = 0; nj < 4; nj++)
                o[ma][nj] = MFMA16(vf[ma][ks], pb[nj], o[ma][nj]);
    }

    short* ob = aout + (size_t)win * 64 * 384 + head * 32;
#pragma unroll
    for (int ma = 0; ma < 2; ma++)
#pragma unroll
        for (int nj = 0; nj < 4; nj++) {
            int i = nj * 16 + l15;
            uint2 pk;
            pk.x = cvt2bf(o[ma][nj][0] * rden[nj], o[ma][nj][1] * rden[nj]);
            pk.y = cvt2bf(o[ma][nj][2] * rden[nj], o[ma][nj][3] * rden[nj]);
            *(uint2*)(ob + (size_t)i * 384 + ma * 16 + g4 * 4) = pk;
        }
}

// ---------------- gemm_proj ----------------
__global__ __launch_bounds__(256, 2) void gemm_proj(
    const short* __restrict__ aout, const short* __restrict__ WtP,
    const float* __restrict__ bproj, float* __restrict__ out) {
    __shared__ short smem[40960];

    const int win = blockIdx.x;
    const int m0 = win * 64;
    const int tid = threadIdx.x, lane = tid & 63, wid = tid >> 6;
    const int l15 = lane & 15, g4 = lane >> 4;
    const int al7 = l15 & 7;
    const int xsw = (g4 ^ ((l15 ^ (l15 >> 2)) & 3)) * 8;

    // ---- A via glds: 48 issues of 1KB (12 per wave), pre-swizzled source ----
#pragma unroll
    for (int j = 0; j < 12; j++) {
        int i = wid * 12 + j;
        int c = i * 64 + lane;
        int row = c / 48, ch = c - row * 48;
        const short* s = aout + (size_t)(m0 + row) * 384 + ((ch ^ (row & 7)) * 8);
        glds16(s, smem + i * 512);
    }

    int bro4[4], bds4[4], bro2[2], bds2[2];
#pragma unroll
    for (int j = 0; j < 4; j++) {
        int i = wid * 4 + j;
        int c = i * 64 + lane;
        int brow = c >> 2, bs = c & 3;
        int sw = (brow ^ (brow >> 2)) & 3;
        bro4[j] = brow * 384 + (bs ^ sw) * 8;
        bds4[j] = i * 512 + lane * 8;
    }
#pragma unroll
    for (int j = 0; j < 2; j++) {
        int i = wid * 2 + j;
        int c = i * 64 + lane;
        int brow = c >> 2, bs = c & 3;
        int sw = (brow ^ (brow >> 2)) & 3;
        bro2[j] = brow * 384 + (bs ^ sw) * 8;
        bds2[j] = i * 512 + lane * 8;
    }

#pragma unroll
    for (int j = 0; j < 4; j++) glds16(WtP + bro4[j], smem + 24576 + bds4[j]);
    __syncthreads();

    const int b_img = win / 144, wrw = win % 144;
    const int wy = wrw / 12, wx = wrw % 12;

    auto epi = [&](const floatx4* accRow, int n) {
        float4 bv = *(const float4*)(bproj + n);
#pragma unroll
        for (int b = 0; b < 4; b++) {
            int t = b * 16 + l15;
            int yy = wy * 8 + (t >> 3) + 4; if (yy >= 96) yy -= 96;
            int xx = wx * 8 + (t & 7) + 4;  if (xx >= 96) xx -= 96;
            floatx4 o = accRow[b];
            o[0] += bv.x; o[1] += bv.y; o[2] += bv.z; o[3] += bv.w;
            *(floatx4*)(&out[((size_t)b_img * 9216 + yy * 96 + xx) * 384 + n]) = o;
        }
    };

    const short* b1 = WtP + (size_t)256 * 384;
    {
        floatx4 acc[4][4];
        panel_k<4>(smem, WtP, b1, bro4, bds4, 4, bro2, bds2, 2,
                   wid * 64, l15, g4, al7, xsw, true, acc);
#pragma unroll
        for (int a = 0; a < 4; a++) epi(acc[a], wid * 64 + a * 16 + g4 * 4);
    }
    {
        floatx4 a2[2][4];
        panel_k<2>(smem, b1, nullptr, bro2, bds2, 2, bro2, bds2, 2,
                   wid * 32, l15, g4, al7, xsw, true, a2);
#pragma unroll
        for (int a = 0; a < 2; a++) epi(a2[a], 256 + wid * 32 + a * 16 + g4 * 4);
    }
}

// ---------------- launcher ----------------
extern "C" void kernel_launch(void* const* d_in, const int* in_sizes, int n_in,
                              void* d_out, int out_size, void* d_ws, size_t ws_size,
                              hipStream_t stream) {
    const float* query = (const float*)d_in[0];
    const float* skipq = (const float*)d_in[1];
    const float* Wqkv  = (const float*)d_in[2];
    const float* bqkv  = (const float*)d_in[3];
    const float* Wskip = (const float*)d_in[4];
    const float* bskip = (const float*)d_in[5];
    const float* rpb   = (const float*)d_in[6];
    const float* Wproj = (const float*)d_in[7];
    const float* bproj = (const float*)d_in[8];
    float* out = (float*)d_out;

    int M = in_sizes[0] / 384;   // total tokens = 147456 for B=16
    int nwin = M / 64;           // 2304

    char* ws = (char*)d_ws;
    size_t off = 0;
    auto alloc = [&](size_t bytes) -> void* {
        void* p = ws + off;
        off = (off + bytes + 255) & ~(size_t)255;
        return p;
    };
    short* Wt     = (short*)alloc((size_t)1152 * 384 * 2);
    short* WtP    = (short*)alloc((size_t)384 * 384 * 2);
    float* bias64 = (float*)alloc((size_t)12 * 64 * 64 * 4);
    short* kbuf   = (short*)alloc((size_t)M * 384 * 2);
    short* vtbuf  = (short*)alloc((size_t)M * 384 * 2);
    short* qbuf   = (short*)alloc((size_t)M * 384 * 2);
    short* aout   = (short*)alloc((size_t)M * 384 * 2);
    (void)ws_size;

    hipLaunchKernelGGL(prep_wt, dim3(216), dim3(256), 0, stream, Wqkv, Wskip, Wt);
    hipLaunchKernelGGL(prep_wtp, dim3(72), dim3(256), 0, stream, Wproj, WtP);
    hipLaunchKernelGGL(prep_bias, dim3(192), dim3(256), 0, stream, rpb, bias64);
    hipLaunchKernelGGL(gemm_qkv, dim3(nwin, 2), dim3(256), 0, stream,
                       query, skipq, Wt, bqkv, bskip, kbuf, vtbuf, qbuf);
    hipLaunchKernelGGL(attn_kernel, dim3(nwin * 12 / 4), dim3(256), 0, stream,
                       kbuf, vtbuf, qbuf, bias64, aout, nwin * 12);
    hipLaunchKernelGGL(gemm_proj, dim3(nwin), dim3(256), 0, stream,
                       aout, WtP, bproj, out);
}

// Round 10
// 577.028 us; speedup vs baseline: 1.8869x; 1.2294x over previous
//
#include <hip/hip_runtime.h>
#include <hip/hip_bf16.h>

// ShiftWindowMSA fused pipeline for MI355X (gfx950).
// R10: barrier-free GEMM K-loops via wave-private B staging.
// Block = 1 window, 512 threads (8 waves). A[64][384] bf16 block-shared in LDS
// (one barrier after gather). Each wave owns 48 output cols; stages its own
// 3 KB B K-slice via global_load_lds into a wave-private LDS dbuf; per-wave
// s_waitcnt vmcnt(3) pipeline, NO barriers in the K-loop.
// gemm_qkv grid (nwin,2): var0 = query -> k,v (24-step chain); var1 = skip -> q.
// gemm_proj: same structure, single 12-step chain. attn unchanged.

typedef __attribute__((ext_vector_type(8))) short short8;
typedef __attribute__((ext_vector_type(4))) float floatx4;

#define MFMA16(a, b, c) __builtin_amdgcn_mfma_f32_16x16x32_bf16(a, b, c, 0, 0, 0)

__device__ __forceinline__ short f2bf(float f) {
    __hip_bfloat16 h = __float2bfloat16(f);
    return *reinterpret_cast<short*>(&h);
}

// packed fp32->bf16 RNE
__device__ __forceinline__ unsigned cvt2bf(float lo, float hi) {
    unsigned r;
    asm("v_cvt_pk_bf16_f32 %0, %1, %2" : "=v"(r) : "v"(lo), "v"(hi));
    return r;
}

__device__ __forceinline__ void glds16(const void* g, void* l) {
    __builtin_amdgcn_global_load_lds(
        (const __attribute__((address_space(1))) void*)g,
        (__attribute__((address_space(3))) void*)l, 16, 0, 0);
}

// ---------------- prep kernels ----------------

__global__ __launch_bounds__(256) void prep_wt(const float* __restrict__ Wqkv,
                                               const float* __restrict__ Wskip,
                                               short* __restrict__ Wt) {
    int tid = blockIdx.x * 256 + threadIdx.x;  // 384*144 = 55296
    if (tid >= 384 * 144) return;
    int k = tid / 144;
    int n8 = (tid % 144) * 8;
#pragma unroll
    for (int e = 0; e < 8; e++) {
        int n = n8 + e;
        float v = (n < 768) ? Wqkv[k * 768 + n]
                            : Wskip[k * 384 + (n - 768)] * 0.17677669529663687f;
        Wt[(size_t)n * 384 + k] = f2bf(v);
    }
}

__global__ __launch_bounds__(256) void prep_wtp(const float* __restrict__ Wproj,
                                                short* __restrict__ WtP) {
    int tid = blockIdx.x * 256 + threadIdx.x;  // 384*48 = 18432
    if (tid >= 384 * 48) return;
    int k = tid / 48;
    int n8 = (tid % 48) * 8;
#pragma unroll
    for (int e = 0; e < 8; e++) {
        int n = n8 + e;
        WtP[(size_t)n * 384 + k] = f2bf(Wproj[k * 384 + n]);
    }
}

__global__ __launch_bounds__(256) void prep_bias(const float* __restrict__ rpb,
                                                 float* __restrict__ bias64) {
    int tid = blockIdx.x * 256 + threadIdx.x;  // 12*64*64 = 49152
    if (tid >= 49152) return;
    int h = tid >> 12;
    int rem = tid & 4095;
    int i = rem >> 6, kk = rem & 63;
    int j = 63 - kk;
    int ridx = 15 * (i >> 3) + (i & 7) + 15 * (j >> 3) + (j & 7);
    bias64[tid] = rpb[ridx * 12 + h];
}

// ---------------- per-wave barrier-free 12-step K-loop ----------------
// A in smem[0..24576) (chunk-swizzled c^(r&7)); wave B dbuf at bwb (2x1536 sh).
// At step kt: wait vmcnt, read A frags + 3 B frags from buf[kt&1], lgkmcnt(0),
// issue glds for step kt+2 (or next panel's 0/1) into buf[kt&1], MFMA x12.
template <bool SWP, bool FIN>
__device__ __forceinline__ void kloop12(
    const short* __restrict__ smemA, short* __restrict__ bwb,
    const short* __restrict__ curSrc, const short* __restrict__ nxtSrc,
    const int (&bso)[3], int l15, int g4, int al7, int brd,
    floatx4 (&acc)[3][4]) {
#pragma unroll
    for (int a = 0; a < 3; a++)
#pragma unroll
        for (int b = 0; b < 4; b++)
#pragma unroll
            for (int r = 0; r < 4; r++) acc[a][b][r] = 0.f;

#pragma unroll
    for (int kt = 0; kt < 12; ++kt) {
        if (FIN && kt == 11) {
            asm volatile("s_waitcnt vmcnt(0)" ::: "memory");
        } else {
            asm volatile("s_waitcnt vmcnt(3)" ::: "memory");
        }
        const int choff = ((kt * 4 + g4) ^ al7) * 8;
        short8 af[4], bfr[3];
#pragma unroll
        for (int b = 0; b < 4; b++)
            af[b] = *(const short8*)(smemA + (b * 16 + l15) * 384 + choff);
        short* hb = bwb + (kt & 1) * 1536;
#pragma unroll
        for (int nj = 0; nj < 3; nj++)
            bfr[nj] = *(const short8*)(hb + (nj * 16 + l15) * 32 + brd);
        __builtin_amdgcn_sched_barrier(0);
        asm volatile("s_waitcnt lgkmcnt(0)" ::: "memory");
        if (kt < 10) {
            int ko = (kt + 2) * 32;
#pragma unroll
            for (int j = 0; j < 3; j++)
                glds16(curSrc + bso[j] + ko, hb + j * 512);
        } else if (!FIN) {
            int ko = (kt - 10) * 32;
#pragma unroll
            for (int j = 0; j < 3; j++)
                glds16(nxtSrc + bso[j] + ko, hb + j * 512);
        }
        __builtin_amdgcn_sched_barrier(0);
        if (SWP) {
#pragma unroll
            for (int a = 0; a < 3; a++)
#pragma unroll
                for (int b = 0; b < 4; b++)
                    acc[a][b] = MFMA16(bfr[a], af[b], acc[a][b]);
        } else {
#pragma unroll
            for (int a = 0; a < 3; a++)
#pragma unroll
                for (int b = 0; b < 4; b++)
                    acc[a][b] = MFMA16(af[b], bfr[a], acc[a][b]);
        }
    }
}

// ---------------- gemm_qkv ----------------
// LDS: A[64][384] 48 KB @0; wave-private B dbuf 8 x (2x1536 sh) @24576. 96 KB.
__global__ __launch_bounds__(512, 1) void gemm_qkv(
    const float* __restrict__ xq, const float* __restrict__ xs,
    const short* __restrict__ Wt,
    const float* __restrict__ bqkv, const float* __restrict__ bskip,
    short* __restrict__ kbuf, short* __restrict__ vtbuf, short* __restrict__ qbuf) {
    __shared__ short smem[49152];

    const int win = blockIdx.x;
    const int var = blockIdx.y;          // 0: A=query -> k,v; 1: A=skip -> q
    const float* __restrict__ src = var ? xs : xq;

    const int tid = threadIdx.x, lane = tid & 63, wid = tid >> 6;
    const int l15 = lane & 15, g4 = lane >> 4;
    const int al7 = l15 & 7;
    const int brd = (g4 ^ ((l15 ^ (l15 >> 2)) & 3)) * 8;

    // ---- A gather: 64 rows x 384 fp32 (shift-window permuted) -> bf16 LDS ----
    {
        int r = tid >> 3, q8 = tid & 7;
        int b = win / 144, wr = win % 144;
        int wy = wr / 12, wx = wr % 12;
        int yy = wy * 8 + (r >> 3) + 4; if (yy >= 96) yy -= 96;
        int xx = wx * 8 + (r & 7) + 4;  if (xx >= 96) xx -= 96;
        const float* rbase = src + ((size_t)b * 9216 + yy * 96 + xx) * 384;
        short* lrow = smem + r * 384;
        int r7 = r & 7;
#pragma unroll
        for (int j = 0; j < 6; j++) {
            int c = q8 + j * 8;
            float4 f0 = *(const float4*)(rbase + c * 8);
            float4 f1 = *(const float4*)(rbase + c * 8 + 4);
            uint4 u;
            u.x = cvt2bf(f0.x, f0.y); u.y = cvt2bf(f0.z, f0.w);
            u.z = cvt2bf(f1.x, f1.y); u.w = cvt2bf(f1.z, f1.w);
            *(uint4*)(lrow + ((c ^ r7) * 8)) = u;
        }
    }

    // ---- wave-private B staging setup ----
    const int sw_st = ((lane >> 2) ^ (lane >> 4)) & 3;
    int bso[3];
#pragma unroll
    for (int j = 0; j < 3; j++)
        bso[j] = (j * 16 + (lane >> 2)) * 384 + (((lane & 3) ^ sw_st) * 8);
    short* bwb = smem + 24576 + wid * 3072;

    const short* src0 = Wt + (size_t)((var ? 768 : 0) + wid * 48) * 384;
    const short* src1 = Wt + (size_t)(384 + wid * 48) * 384;  // v (var0 only)

    // prologue: stage steps 0,1 of first panel
#pragma unroll
    for (int j = 0; j < 3; j++) glds16(src0 + bso[j], bwb + j * 512);
#pragma unroll
    for (int j = 0; j < 3; j++) glds16(src0 + bso[j] + 32, bwb + 1536 + j * 512);
    __syncthreads();  // A ready; drains all vmcnt

    floatx4 acc[3][4];
    if (var == 0) {
        // ---- k panel (swapped), chained into v panel ----
        kloop12<true, false>(smem, bwb, src0, src1, bso, l15, g4, al7, brd, acc);
#pragma unroll
        for (int a = 0; a < 3; a++) {
            int nm = wid * 48 + a * 16 + g4 * 4;
            int head = nm >> 5, d0 = nm & 31;
            float4 bv = *(const float4*)(bqkv + nm);
            short* dst = kbuf + (size_t)(win * 12 + head) * 2048 + d0;
#pragma unroll
            for (int b = 0; b < 4; b++) {
                int t = b * 16 + l15;
                uint2 pk;
                pk.x = cvt2bf(acc[a][b][0] + bv.x, acc[a][b][1] + bv.y);
                pk.y = cvt2bf(acc[a][b][2] + bv.z, acc[a][b][3] + bv.w);
                *(uint2*)(dst + (size_t)t * 32) = pk;
            }
        }
        // ---- v panel (unswapped, final) ----
        kloop12<false, true>(smem, bwb, src1, nullptr, bso, l15, g4, al7, brd, acc);
#pragma unroll
        for (int nj = 0; nj < 3; nj++) {
            int nm = wid * 48 + nj * 16 + l15;
            int head = nm >> 5, d = nm & 31;
            float bvs = bqkv[384 + nm];
            short* dst = vtbuf + ((size_t)(win * 12 + head) * 32 + d) * 64;
#pragma unroll
            for (int mi = 0; mi < 4; mi++) {
                int t0 = mi * 16 + g4 * 4;
                uint2 pk;
                pk.x = cvt2bf(acc[nj][mi][0] + bvs, acc[nj][mi][1] + bvs);
                pk.y = cvt2bf(acc[nj][mi][2] + bvs, acc[nj][mi][3] + bvs);
                *(uint2*)(dst + t0) = pk;
            }
        }
    } else {
        // ---- q panel (swapped, final; W pre-scaled, bias scaled here) ----
        kloop12<true, true>(smem, bwb, src0, nullptr, bso, l15, g4, al7, brd, acc);
        const float scl = 0.17677669529663687f;
#pragma unroll
        for (int a = 0; a < 3; a++) {
            int nm = wid * 48 + a * 16 + g4 * 4;
            int head = nm >> 5, d0 = nm & 31;
            float4 bv = *(const float4*)(bskip + nm);
            short* dst = qbuf + (size_t)(win * 12 + head) * 2048 + d0;
#pragma unroll
            for (int b = 0; b < 4; b++) {
                int t = b * 16 + l15;
                uint2 pk;
                pk.x = cvt2bf(acc[a][b][0] + bv.x * scl, acc[a][b][1] + bv.y * scl);
                pk.y = cvt2bf(acc[a][b][2] + bv.z * scl, acc[a][b][3] + bv.w * scl);
                *(uint2*)(dst + (size_t)t * 32) = pk;
            }
        }
    }
}

// ---------------- attention ----------------
__global__ __launch_bounds__(256) void attn_kernel(
    const short* __restrict__ kbuf, const short* __restrict__ vtbuf,
    const short* __restrict__ qbuf, const float* __restrict__ bias64,
    short* __restrict__ aout, int ntask) {
    __shared__ short lps[18432];  // 4 waves x 64 x 72
    int lane = threadIdx.x & 63, wid = threadIdx.x >> 6;
    int task = blockIdx.x * 4 + wid;
    if (task >= ntask) return;
    int win = task / 12, head = task % 12;
    int l15 = lane & 15, g4 = lane >> 4;

    const short* kb = kbuf + (size_t)task * 2048;
    const short* qb = qbuf + (size_t)task * 2048;
    const short* vb = vtbuf + (size_t)task * 2048;

    short8 kf[4], qf[4], vf[2][2];
#pragma unroll
    for (int mi = 0; mi < 4; mi++)
        kf[mi] = *(const short8*)(kb + (mi * 16 + l15) * 32 + g4 * 8);
#pragma unroll
    for (int nj = 0; nj < 4; nj++)
        qf[nj] = *(const short8*)(qb + (nj * 16 + l15) * 32 + g4 * 8);
#pragma unroll
    for (int ma = 0; ma < 2; ma++)
#pragma unroll
        for (int ks = 0; ks < 2; ks++)
            vf[ma][ks] = *(const short8*)(vb + (ma * 16 + l15) * 64 + ks * 32 + g4 * 8);

    floatx4 st[4][4];
#pragma unroll
    for (int mi = 0; mi < 4; mi++)
#pragma unroll
        for (int nj = 0; nj < 4; nj++)
#pragma unroll
            for (int r = 0; r < 4; r++) st[mi][nj][r] = 0.f;

#pragma unroll
    for (int mi = 0; mi < 4; mi++)
#pragma unroll
        for (int nj = 0; nj < 4; nj++)
            st[mi][nj] = MFMA16(kf[mi], qf[nj], st[mi][nj]);  // S^T[kk][i]

    const float* bb = bias64 + head * 4096;
#pragma unroll
    for (int nj = 0; nj < 4; nj++) {
        int i = nj * 16 + l15;
#pragma unroll
        for (int mi = 0; mi < 4; mi++) {
            floatx4 b4 = *(const floatx4*)(bb + i * 64 + mi * 16 + g4 * 4);
            st[mi][nj] += b4;
        }
    }

    int wr = win % 144;
    int wy = wr / 12, wx = wr % 12;
    if (wy == 11 || wx == 11) {
        int wy11 = (wy == 11), wx11 = (wx == 11);
        int ri[4];
#pragma unroll
        for (int nj = 0; nj < 4; nj++) {
            int t = nj * 16 + l15;
            int hh = wy11 ? (((t >> 3) >= 4) ? 2 : 1) : 0;
            int ww = wx11 ? (((t & 7) >= 4) ? 2 : 1) : 0;
            ri[nj] = hh * 3 + ww;
        }
#pragma unroll
        for (int mi = 0; mi < 4; mi++)
#pragma unroll
            for (int r = 0; r < 4; r++) {
                int t = mi * 16 + g4 * 4 + r;
                int hh = wy11 ? (((t >> 3) >= 4) ? 2 : 1) : 0;
                int ww = wx11 ? (((t & 7) >= 4) ? 2 : 1) : 0;
                int rk = hh * 3 + ww;
#pragma unroll
                for (int nj = 0; nj < 4; nj++)
                    if (rk != ri[nj]) st[mi][nj][r] -= 100.0f;
            }
    }

    float rden[4];
#pragma unroll
    for (int nj = 0; nj < 4; nj++) {
        float m = -1e30f;
#pragma unroll
        for (int mi = 0; mi < 4; mi++)
#pragma unroll
            for (int r = 0; r < 4; r++) m = fmaxf(m, st[mi][nj][r]);
        m = fmaxf(m, __shfl_xor(m, 16));
        m = fmaxf(m, __shfl_xor(m, 32));
        float s = 0.f;
#pragma unroll
        for (int mi = 0; mi < 4; mi++)
#pragma unroll
            for (int r = 0; r < 4; r++) {
                float p = __expf(st[mi][nj][r] - m);
                st[mi][nj][r] = p;
                s += p;
            }
        s += __shfl_xor(s, 16);
        s += __shfl_xor(s, 32);
        rden[nj] = 1.0f / s;
    }

    short* Lp = lps + wid * 4608;  // [64][72]
#pragma unroll
    for (int mi = 0; mi < 4; mi++)
#pragma unroll
        for (int nj = 0; nj < 4; nj++) {
            uint2 pk;
            pk.x = cvt2bf(st[mi][nj][0], st[mi][nj][1]);
            pk.y = cvt2bf(st[mi][nj][2], st[mi][nj][3]);
            *(uint2*)(Lp + (nj * 16 + l15) * 72 + mi * 16 + g4 * 4) = pk;
        }

    floatx4 o[2][4];
#pragma unroll
    for (int ma = 0; ma < 2; ma++)
#pragma unroll
        for (int nj = 0; nj < 4; nj++)
#pragma unroll
            for (int r = 0; r < 4; r++) o[ma][nj][r] = 0.f;
#pragma unroll
    for (int ks = 0; ks < 2; ks++) {
        short8 pb[4];
#pragma unroll
        for (int nj = 0; nj < 4; nj++)
            pb[nj] = *(const short8*)(Lp + (nj * 16 + l15) * 72 + ks * 32 + g4 * 8);
#pragma unroll
        for (int ma = 0; ma < 2; ma++)
#pragma unroll
            for (int nj = 0; nj < 4; nj++)
                o[ma][nj] = MFMA16(vf[ma][ks], pb[nj], o[ma][nj]);
    }

    short* ob = aout + (size_t)win * 64 * 384 + head * 32;
#pragma unroll
    for (int ma = 0; ma < 2; ma++)
#pragma unroll
        for (int nj = 0; nj < 4; nj++) {
            int i = nj * 16 + l15;
            uint2 pk;
            pk.x = cvt2bf(o[ma][nj][0] * rden[nj], o[ma][nj][1] * rden[nj]);
            pk.y = cvt2bf(o[ma][nj][2] * rden[nj], o[ma][nj][3] * rden[nj]);
            *(uint2*)(ob + (size_t)i * 384 + ma * 16 + g4 * 4) = pk;
        }
}

// ---------------- gemm_proj ----------------
__global__ __launch_bounds__(512, 1) void gemm_proj(
    const short* __restrict__ aout, const short* __restrict__ WtP,
    const float* __restrict__ bproj, float* __restrict__ out) {
    __shared__ short smem[49152];

    const int win = blockIdx.x;
    const int m0 = win * 64;
    const int tid = threadIdx.x, lane = tid & 63, wid = tid >> 6;
    const int l15 = lane & 15, g4 = lane >> 4;
    const int al7 = l15 & 7;
    const int brd = (g4 ^ ((l15 ^ (l15 >> 2)) & 3)) * 8;

    // ---- A via glds: 48 issues of 1KB (6 per wave), pre-swizzled source ----
#pragma unroll
    for (int j = 0; j < 6; j++) {
        int i = wid * 6 + j;
        int c = i * 64 + lane;
        int row = c / 48, ch = c - row * 48;
        const short* s = aout + (size_t)(m0 + row) * 384 + ((ch ^ (row & 7)) * 8);
        glds16(s, smem + i * 512);
    }

    const int sw_st = ((lane >> 2) ^ (lane >> 4)) & 3;
    int bso[3];
#pragma unroll
    for (int j = 0; j < 3; j++)
        bso[j] = (j * 16 + (lane >> 2)) * 384 + (((lane & 3) ^ sw_st) * 8);
    short* bwb = smem + 24576 + wid * 3072;
    const short* src0 = WtP + (size_t)(wid * 48) * 384;

#pragma unroll
    for (int j = 0; j < 3; j++) glds16(src0 + bso[j], bwb + j * 512);
#pragma unroll
    for (int j = 0; j < 3; j++) glds16(src0 + bso[j] + 32, bwb + 1536 + j * 512);
    __syncthreads();

    floatx4 acc[3][4];
    kloop12<true, true>(smem, bwb, src0, nullptr, bso, l15, g4, al7, brd, acc);

    const int b_img = win / 144, wrw = win % 144;
    const int wy = wrw / 12, wx = wrw % 12;
#pragma unroll
    for (int a = 0; a < 3; a++) {
        int n = wid * 48 + a * 16 + g4 * 4;
        float4 bv = *(const float4*)(bproj + n);
#pragma unroll
        for (int b = 0; b < 4; b++) {
            int t = b * 16 + l15;
            int yy = wy * 8 + (t >> 3) + 4; if (yy >= 96) yy -= 96;
            int xx = wx * 8 + (t & 7) + 4;  if (xx >= 96) xx -= 96;
            floatx4 o = acc[a][b];
            o[0] += bv.x; o[1] += bv.y; o[2] += bv.z; o[3] += bv.w;
            *(floatx4*)(&out[((size_t)b_img * 9216 + yy * 96 + xx) * 384 + n]) = o;
        }
    }
}

// ---------------- launcher ----------------
extern "C" void kernel_launch(void* const* d_in, const int* in_sizes, int n_in,
                              void* d_out, int out_size, void* d_ws, size_t ws_size,
                              hipStream_t stream) {
    const float* query = (const float*)d_in[0];
    const float* skipq = (const float*)d_in[1];
    const float* Wqkv  = (const float*)d_in[2];
    const float* bqkv  = (const float*)d_in[3];
    const float* Wskip = (const float*)d_in[4];
    const float* bskip = (const float*)d_in[5];
    const float* rpb   = (const float*)d_in[6];
    const float* Wproj = (const float*)d_in[7];
    const float* bproj = (const float*)d_in[8];
    float* out = (float*)d_out;

    int M = in_sizes[0] / 384;   // total tokens = 147456 for B=16
    int nwin = M / 64;           // 2304

    char* ws = (char*)d_ws;
    size_t off = 0;
    auto alloc = [&](size_t bytes) -> void* {
        void* p = ws + off;
        off = (off + bytes + 255) & ~(size_t)255;
        return p;
    };
    short* Wt     = (short*)alloc((size_t)1152 * 384 * 2);
    short* WtP    = (short*)alloc((size_t)384 * 384 * 2);
    float* bias64 = (float*)alloc((size_t)12 * 64 * 64 * 4);
    short* kbuf   = (short*)alloc((size_t)M * 384 * 2);
    short* vtbuf  = (short*)alloc((size_t)M * 384 * 2);
    short* qbuf   = (short*)alloc((size_t)M * 384 * 2);
    short* aout   = (short*)alloc((size_t)M * 384 * 2);
    (void)ws_size;

    hipLaunchKernelGGL(prep_wt, dim3(216), dim3(256), 0, stream, Wqkv, Wskip, Wt);
    hipLaunchKernelGGL(prep_wtp, dim3(72), dim3(256), 0, stream, Wproj, WtP);
    hipLaunchKernelGGL(prep_bias, dim3(192), dim3(256), 0, stream, rpb, bias64);
    hipLaunchKernelGGL(gemm_qkv, dim3(nwin, 2), dim3(512), 0, stream,
                       query, skipq, Wt, bqkv, bskip, kbuf, vtbuf, qbuf);
    hipLaunchKernelGGL(attn_kernel, dim3(nwin * 12 / 4), dim3(256), 0, stream,
                       kbuf, vtbuf, qbuf, bias64, aout, nwin * 12);
    hipLaunchKernelGGL(gemm_proj, dim3(nwin), dim3(512), 0, stream,
                       aout, WtP, bproj, out);
}